// Round 4
// baseline (117.434 us; speedup 1.0000x reference)
//
#include <hip/hip_runtime.h>

// TensorTrain: out[b] = first(x0) . M0(x1) . ... . M29(x30) . last(x31)
// with R=16, D=32, B=262144, selection bits in {0,1}.
//
// Meet-in-the-middle: out = V16[p] . W16[s], p = x0..x15 (MSB first),
// s = x16..x31. Three dispatches:
//   stage1: blocks 0..33 build SHARED byte tables once (P8 = M7..M14
//           products, Q8 = M15..M22, V8 = first@M0..M6, W8 = M23..M29@last)
//           from bit-deinterleaved LDS-staged cores; blocks 34..1023
//           concurrently pack X (33.5 MB) into 1 MB of (p<<16)|s words.
//   stage2: V16[e] = V8[e>>8] @ P8[e&255]; W16[e] = Q8[e>>8] @ W8[e&255].
//   stage3: per element: 4 B packed index, two 64 B gathers, 16-wide dot.
//
// Round-3 lessons kept: ROLLED outer loops around one unrolled 16x16 matvec
// (I-cache; round-2's 90 KB straight-line bodies were fetch-bound at 7%
// VALUBusy). Round-3 waste removed: the old tt_build rebuilt identical
// tables in every one of 512 blocks; tables are now built once.

#define R 16
#define TT_D 32
#define BATCH 262144

// workspace layout, in floats
#define OFF_V16  0                      // 65536 x 16  (4 MB)
#define OFF_W16  1048576                // 65536 x 16  (4 MB)
#define OFF_P8   2097152                // 256 x 16 x 16
#define OFF_Q8   (OFF_P8 + 65536)       // 256 x 16 x 16
#define OFF_V8   (OFF_Q8 + 65536)       // 256 x 16
#define OFF_W8   (OFF_V8 + 4096)        // 256 x 16
#define OFF_PK   (OFF_W8 + 4096)        // BATCH u32 packed indices
#define WS_FLOATS (OFF_PK + BATCH)      // ~10 MB

#define NBLK1 1024                      // stage-1 grid
#define NTAB  34                        // table-builder blocks in stage 1

// u (registers, row-vec) = u @ M, M row-major 16x16 (LDS or global).
// Inner fully unrolled: static indexing keeps u/nv in VGPRs.
__device__ __forceinline__ void rowvec_mat(const float* __restrict__ M,
                                           float* __restrict__ u) {
    float nv[R];
    #pragma unroll
    for (int s = 0; s < R; s++) nv[s] = 0.f;
    #pragma unroll
    for (int t2 = 0; t2 < R; t2++) {
        const float a = u[t2];
        #pragma unroll
        for (int s = 0; s < R; s++) nv[s] += a * M[t2 * 16 + s];
    }
    #pragma unroll
    for (int s = 0; s < R; s++) u[s] = nv[s];
}

// w (registers, col-vec) = M @ w.
__device__ __forceinline__ void mat_colvec(const float* __restrict__ M,
                                           float* __restrict__ w) {
    float nw[R];
    #pragma unroll
    for (int r2 = 0; r2 < R; r2++) {
        float a = 0.f;
        #pragma unroll
        for (int k = 0; k < R; k++) a += M[r2 * 16 + k] * w[k];
        nw[r2] = a;
    }
    #pragma unroll
    for (int r2 = 0; r2 < R; r2++) w[r2] = nw[r2];
}

// ---------------------------------------------------------------------------
// Stage 1: shared byte tables (blocks 0..33) + X packing (blocks 34..1023).
// scm layout: [core][bit][r*16+s], 512 floats/core -> within a wave the only
// address divergence in chain reads is the 2 bit-planes: <=2 distinct LDS
// addresses per read instruction = conflict-free broadcast.
__global__ __launch_bounds__(256) void tt_stage1(const int* __restrict__ X,
                                                 const float* __restrict__ cf,
                                                 const float* __restrict__ cm,
                                                 const float* __restrict__ cl,
                                                 float* __restrict__ ws) {
    __shared__ float scm[8 * 512];      // 16 KB
    const int blk = blockIdx.x;
    const int t = threadIdx.x;

    if (blk < NTAB) {
        // ---- stage the cores this block needs, bit-deinterleaved ----
        int cbase, ncore;
        if (blk < 16)       { cbase = 7;  ncore = 8; }   // P8: M7..M14
        else if (blk < 32)  { cbase = 15; ncore = 8; }   // Q8: M15..M22
        else if (blk == 32) { cbase = 0;  ncore = 7; }   // V8: M0..M6
        else                { cbase = 23; ncore = 7; }   // W8: M23..M29
        const float2* cm2 = (const float2*)(cm + cbase * 512);
        for (int j = t; j < ncore * 256; j += 256) {
            const float2 vv = cm2[j];                    // coalesced 8B loads
            const int ci = j >> 8, idx = j & 255;
            scm[ci * 512 + idx] = vv.x;                  // bit-0 plane
            scm[ci * 512 + 256 + idx] = vv.y;            // bit-1 plane
        }
        __syncthreads();

        if (blk < 32) {
            // P8[e] (or Q8[e]) row r: product of 8 staged cores, bits of e
            // MSB-first. 16 entries per block, thread = (entry, row).
            const bool isP = (blk < 16);
            const int e = (isP ? blk : blk - 16) * 16 + (t >> 4), r = t & 15;
            float u[R];
            const float* M0 = scm + ((e >> 7) & 1) * 256;
            #pragma unroll
            for (int s = 0; s < R; s++) u[s] = M0[r * 16 + s];
            for (int k = 1; k < 8; k++)
                rowvec_mat(scm + k * 512 + ((e >> (7 - k)) & 1) * 256, u);
            float* o = ws + (isP ? OFF_P8 : OFF_Q8) + e * 256 + r * 16;
            #pragma unroll
            for (int s = 0; s < R; s++) o[s] = u[s];
        } else if (blk == 32) {
            // V8[e] = first(x0) @ M0(x1) @ ... @ M6(x7), e = t.
            const int e = t;
            float u[R];
            #pragma unroll
            for (int s = 0; s < R; s++) u[s] = cf[s * 2 + ((e >> 7) & 1)];
            for (int k = 0; k < 7; k++)
                rowvec_mat(scm + k * 512 + ((e >> (6 - k)) & 1) * 256, u);
            float* o = ws + OFF_V8 + e * 16;
            #pragma unroll
            for (int s = 0; s < R; s++) o[s] = u[s];
        } else {
            // W8[e] = M23(x24) @ ... @ M29(x30) @ last(x31), e = t.
            // Local core j = M(23+j) selects bit e>>(7-j); innermost first.
            const int e = t;
            float w[R];
            #pragma unroll
            for (int r2 = 0; r2 < R; r2++) w[r2] = cl[r2 * 2 + (e & 1)];
            for (int j = 6; j >= 0; j--)
                mat_colvec(scm + j * 512 + ((e >> (7 - j)) & 1) * 256, w);
            float* o = ws + OFF_W8 + e * 16;
            #pragma unroll
            for (int r2 = 0; r2 < R; r2++) o[r2] = w[r2];
        }
    } else {
        // ---- pack X: 33.5 MB -> 1 MB of (p<<16)|s ----
        unsigned* pk = (unsigned*)(ws + OFF_PK);
        const int stride = (NBLK1 - NTAB) * 256;
        for (int b = (blk - NTAB) * 256 + t; b < BATCH; b += stride) {
            const int4* Xr = (const int4*)(X + (size_t)b * TT_D);
            unsigned p = 0, s = 0;
            #pragma unroll
            for (int q = 0; q < 4; q++) {
                const int4 c = Xr[q];
                p = (p << 4) | ((unsigned)(c.x & 1) << 3) | ((unsigned)(c.y & 1) << 2)
                             | ((unsigned)(c.z & 1) << 1) | (unsigned)(c.w & 1);
            }
            #pragma unroll
            for (int q = 4; q < 8; q++) {
                const int4 c = Xr[q];
                s = (s << 4) | ((unsigned)(c.x & 1) << 3) | ((unsigned)(c.y & 1) << 2)
                             | ((unsigned)(c.z & 1) << 1) | (unsigned)(c.w & 1);
            }
            pk[b] = (p << 16) | s;
        }
    }
}

// ---------------------------------------------------------------------------
// Stage 2: expand byte tables to 16-bit tables. One thread per entry.
// Blocks 0..255: V16[blk*256+t] = V8[blk] @ P8[t] (per-thread 1 KB L2 read).
// Blocks 256..511: W16 side; Q8[hi] is block-uniform -> staged in LDS,
// mat_colvec reads are same-address broadcasts.
__global__ __launch_bounds__(256) void tt_stage2(float* __restrict__ ws) {
    __shared__ float sQ[256];
    const int blk = blockIdx.x;
    const int t = threadIdx.x;
    if (blk < 256) {
        const int hi = blk, lo = t;
        float u[R];
        const float* v8 = ws + OFF_V8 + hi * 16;         // block-uniform 64 B
        #pragma unroll
        for (int k = 0; k < R; k++) u[k] = v8[k];
        rowvec_mat(ws + OFF_P8 + lo * 256, u);
        float* o = ws + OFF_V16 + (size_t)(hi * 256 + lo) * 16;
        #pragma unroll
        for (int s = 0; s < R; s++) o[s] = u[s];
    } else {
        const int hi = blk - 256, lo = t;
        sQ[t] = ws[OFF_Q8 + hi * 256 + t];               // coalesced 1 KB
        __syncthreads();
        float w[R];
        const float* w8 = ws + OFF_W8 + lo * 16;
        #pragma unroll
        for (int k = 0; k < R; k++) w[k] = w8[k];
        mat_colvec(sQ, w);
        float* o = ws + OFF_W16 + (size_t)(hi * 256 + lo) * 16;
        #pragma unroll
        for (int r2 = 0; r2 < R; r2++) o[r2] = w[r2];
    }
}

// ---------------------------------------------------------------------------
// Stage 3: per element: 4 B packed index read, two 64 B gathers, dot.
__global__ __launch_bounds__(256) void tt_gather(const float* __restrict__ ws,
                                                 float* __restrict__ out) {
    const int b = blockIdx.x * 256 + threadIdx.x;
    const unsigned pk = ((const unsigned*)(ws + OFF_PK))[b];
    const unsigned p = pk >> 16, s = pk & 0xffffu;
    const float4* v = (const float4*)(ws + OFF_V16 + (size_t)p * 16);
    const float4* w = (const float4*)(ws + OFF_W16 + (size_t)s * 16);
    float acc = 0.f;
    #pragma unroll
    for (int k = 0; k < 4; k++) {
        const float4 a = v[k], c = w[k];
        acc += a.x * c.x + a.y * c.y + a.z * c.z + a.w * c.w;
    }
    out[b] = acc;
}

// ---------------------------------------------------------------------------
// Fallback: direct per-thread chain (used only if ws too small).
__global__ __launch_bounds__(256) void tt_direct(const int* __restrict__ X,
                                                 const float* __restrict__ cf,
                                                 const float* __restrict__ cm,
                                                 const float* __restrict__ cl,
                                                 float* __restrict__ out) {
    __shared__ float scm[30 * 16 * 16 * 2];
    for (int i = threadIdx.x; i < 30 * 16 * 16 * 2; i += blockDim.x) scm[i] = cm[i];
    __syncthreads();
    const int b = blockIdx.x * blockDim.x + threadIdx.x;
    if (b >= BATCH) return;
    const int* xr = X + (size_t)b * TT_D;
    float v[R], nv[R];
    const int x0 = xr[0] & 1;
    #pragma unroll
    for (int rr = 0; rr < R; rr++) v[rr] = cf[rr * 2 + x0];
    for (int i = 1; i <= 30; i++) {
        const int bit = xr[i] & 1;
        const float* M = scm + (i - 1) * 512;
        #pragma unroll
        for (int s2 = 0; s2 < R; s2++) {
            float acc = 0.f;
            #pragma unroll
            for (int rr = 0; rr < R; rr++) acc += v[rr] * M[(rr * 16 + s2) * 2 + bit];
            nv[s2] = acc;
        }
        #pragma unroll
        for (int s2 = 0; s2 < R; s2++) v[s2] = nv[s2];
    }
    const int xl = xr[31] & 1;
    float acc = 0.f;
    #pragma unroll
    for (int rr = 0; rr < R; rr++) acc += v[rr] * cl[rr * 2 + xl];
    out[b] = acc;
}

extern "C" void kernel_launch(void* const* d_in, const int* in_sizes, int n_in,
                              void* d_out, int out_size, void* d_ws, size_t ws_size,
                              hipStream_t stream) {
    const int* X = (const int*)d_in[0];
    const float* cf = (const float*)d_in[1];
    const float* cm = (const float*)d_in[2];
    const float* cl = (const float*)d_in[3];
    float* out = (float*)d_out;

    if (ws_size >= (size_t)WS_FLOATS * sizeof(float)) {
        float* ws = (float*)d_ws;
        tt_stage1<<<NBLK1, 256, 0, stream>>>(X, cf, cm, cl, ws);
        tt_stage2<<<512, 256, 0, stream>>>(ws);
        tt_gather<<<BATCH / 256, 256, 0, stream>>>(ws, out);
    } else {
        tt_direct<<<(BATCH + 255) / 256, 256, 0, stream>>>(X, cf, cm, cl, out);
    }
}